// Round 7
// baseline (523.885 us; speedup 1.0000x reference)
//
#include <hip/hip_runtime.h>

#define DIM   256
#define HW_   1024
#define NROWS 32768
#define KEMB  4096

// ---------------- ws layout ----------------
// [0,       131072)  int    idx[32768]
// [131072,  262144)  float  S[32768]
// [262144,  278528)  float  E[4096]
// [278528,  278536)  double loss_sum
// [278536,  278540)  int    done
// [278592,  409664)  int    cnt[32768]
// [409664,  540736)  uint   rowmin_enc[32768]
// [540736,  1589312) int    cand[32768][8]
// [1589312, 3686464) short  ebuf[4096*512]  (bf16, 32x32-frag-major)
#define WS_S_OFF    131072
#define WS_E_OFF    262144
#define WS_LOSS_OFF 278528
#define WS_DONE_OFF 278536
#define WS_CNT_OFF  278592
#define WS_RMIN_OFF 409664
#define WS_CAND_OFF 540736
#define WS_EBUF_OFF 1589312
#define WS_NEEDED   3686464
#define RESCUE_W    1.5e-4f

typedef __attribute__((ext_vector_type(8)))  short bf16x8;
typedef __attribute__((ext_vector_type(16))) float f32x16;

__device__ __forceinline__ unsigned short f2bf(float v) {
  unsigned u = __float_as_uint(v);
  return (unsigned short)((u + 0x7FFFu + ((u >> 16) & 1u)) >> 16);
}
__device__ __forceinline__ unsigned encf(float f) {
  unsigned u = __float_as_uint(f);
  return ((int)u < 0) ? ~u : (u | 0x80000000u);
}
__device__ __forceinline__ float decf(unsigned k) {
  unsigned u = (k & 0x80000000u) ? (k ^ 0x80000000u) : ~k;
  return __uint_as_float(u);
}

// ---------- numpy-pairwise row sums of squares ----------
__device__ __forceinline__ float np_sumsq_128(const float* q, int stride) {
#pragma clang fp contract(off)
  float r[8];
#pragma unroll
  for (int i = 0; i < 8; ++i) { float v = q[i * stride]; r[i] = v * v; }
  for (int blk = 8; blk < 128; blk += 8) {
#pragma unroll
    for (int i = 0; i < 8; ++i) {
      float v = q[(blk + i) * stride];
      float sq = v * v;
      r[i] = r[i] + sq;
    }
  }
  return ((r[0] + r[1]) + (r[2] + r[3])) + ((r[4] + r[5]) + (r[6] + r[7]));
}

// ---------- prep: norms [0,144) + pack [144,656) + init [656,784) ----------
// pack tile (jg, kf): lane l holds e[j = jg*32 + (l&31)][k = kf*16 + (l>>5)*8 + i]
// flat short offset = ((jg*16 + kf)*64 + l)*8  -> 16 KB contiguous per jg.
__global__ __launch_bounds__(256) void prep_kernel(
    const float* __restrict__ z, const float* __restrict__ emb,
    float* __restrict__ S, float* __restrict__ E, short* __restrict__ ebuf,
    int* __restrict__ cnt_g, unsigned* __restrict__ rowmin_enc,
    double* __restrict__ loss_sum, int* __restrict__ done, int do_filter) {
#pragma clang fp contract(off)
  if (blockIdx.x < 144) {
    int t = blockIdx.x * 256 + threadIdx.x;
    if (t == 0) { loss_sum[0] = 0.0; done[0] = 0; }
    if (t < NROWS) {
      int b = t >> 10, hw = t & 1023;
      const float* p = z + (size_t)b * (DIM * HW_) + hw;
      float s0 = np_sumsq_128(p, HW_);
      float s1 = np_sumsq_128(p + 128 * HW_, HW_);
      S[t] = s0 + s1;
    } else if (t < NROWS + KEMB) {
      int j = t - NROWS;
      const float* p = emb + (size_t)j * DIM;
      float s0 = np_sumsq_128(p, 1);
      float s1 = np_sumsq_128(p + 128, 1);
      E[j] = s0 + s1;
    }
  } else if (blockIdx.x < 656) {
    if (!do_filter) return;
    int u = (blockIdx.x - 144) * 256 + threadIdx.x;   // 0..131071
    int l = u & 63;
    int kf = (u >> 6) & 15;
    int jg = u >> 10;
    int j = jg * 32 + (l & 31);
    int kb = kf * 16 + (l >> 5) * 8;
    const float* p = emb + (size_t)j * DIM + kb;
    short out[8];
#pragma unroll
    for (int i = 0; i < 8; ++i) out[i] = (short)f2bf(p[i]);
    *(bf16x8*)(ebuf + (size_t)u * 8) = *(bf16x8*)out;
  } else {
    if (!do_filter) return;
    int i = (blockIdx.x - 656) * 256 + threadIdx.x;   // 0..32767
    cnt_g[i] = 0;
    rowmin_enc[i] = 0xFFFFFFFFu;
  }
}

// ---------- A-frag load: 64 rows x 256 k per wave, bf16 (R6-proven) ----------
// A lane layout: [dim: l&31][k: (l>>5)*8 + i], kf tiles of 16 k.
__device__ __forceinline__ void load_a_frags(
    const float* __restrict__ z, int nbase, int w, int lane, bf16x8 a[2][16]) {
  int b = nbase >> 10, hwb = nbase & 1023;     // 256 | 1024: no b straddle
  const float* zw = z + (size_t)b * (DIM * HW_) + hwb + w * 64 + (lane & 31);
#pragma unroll
  for (int mt = 0; mt < 2; ++mt) {
#pragma unroll
    for (int kf = 0; kf < 16; ++kf) {
      short tmp[8];
#pragma unroll
      for (int i = 0; i < 8; ++i) {
        int k = kf * 16 + (lane >> 5) * 8 + i;
        tmp[i] = (short)f2bf(zw[mt * 32 + (size_t)k * HW_]);
      }
      a[mt][kf] = *(bf16x8*)tmp;
    }
  }
}

// ---------- sweep kernels: 32x32x16 MFMA, B double-buffered in LDS ----------
// Grid 512 x 256 thr (4 waves). Block = rowgroup (256 rows; wave w owns
// [nbase + w*64, +64) as 2 m-tiles of 32) x j-quarter (1024 j = 32 tiles of
// 32 j). Per tile: 16 KB ebuf chunk staged to LDS (dbuf, depth-2 reg
// prefetch, 1 barrier/tile); all 4 waves share it. 2 blocks/CU overlap
// barrier bubbles. C/D: col=l&31, row=(reg&3)+8*(reg>>2)+4*(l>>5) [proven].

__global__ __launch_bounds__(256, 2) void sweep0_kernel(
    const float* __restrict__ z, const short* __restrict__ ebuf,
    const float* __restrict__ E, unsigned* __restrict__ rowmin_enc) {
  __shared__ float4 btile[2][1024];            // 2 x 16 KB
  const int t = threadIdx.x, w = t >> 6, lane = t & 63;
  const int rg = blockIdx.x >> 2, jq = blockIdx.x & 3;
  const int nbase = rg * 256;

  bf16x8 a[2][16];
  load_a_frags(z, nbase, w, lane, a);

  const float4* esrc = (const float4*)ebuf;
  const int jg0 = jq * 32;
  float4 pf[4];
  // stage tile 0 directly, prefetch tile 1
#pragma unroll
  for (int q = 0; q < 4; ++q)
    btile[0][q * 256 + t] = esrc[(size_t)jg0 * 1024 + q * 256 + t];
#pragma unroll
  for (int q = 0; q < 4; ++q)
    pf[q] = esrc[(size_t)(jg0 + 1) * 1024 + q * 256 + t];

  float runmin[2][16];
#pragma unroll
  for (int mt = 0; mt < 2; ++mt)
#pragma unroll
    for (int r = 0; r < 16; ++r) runmin[mt][r] = 3.0e38f;

  for (int jt = 0; jt < 32; ++jt) {
    const int cur = jt & 1;
    __syncthreads();                           // btile[cur] ready; [cur^1] free
    if (jt + 1 < 32) {
#pragma unroll
      for (int q = 0; q < 4; ++q) btile[cur ^ 1][q * 256 + t] = pf[q];
    }
    if (jt + 2 < 32) {
#pragma unroll
      for (int q = 0; q < 4; ++q)
        pf[q] = esrc[(size_t)(jg0 + jt + 2) * 1024 + q * 256 + t];
    }
    f32x16 acc0 = {0}, acc1 = {0};
    const bf16x8* bt = (const bf16x8*)btile[cur];
#pragma unroll
    for (int kf = 0; kf < 16; ++kf) {
      bf16x8 bf = bt[kf * 64 + lane];
      acc0 = __builtin_amdgcn_mfma_f32_32x32x16_bf16(a[0][kf], bf, acc0, 0, 0, 0);
      acc1 = __builtin_amdgcn_mfma_f32_32x32x16_bf16(a[1][kf], bf, acc1, 0, 0, 0);
    }
    const int jb = jq * 1024 + jt * 32;
    float Ej = E[jb + (lane & 31)];
#pragma unroll
    for (int r = 0; r < 16; ++r) {
      runmin[0][r] = fminf(runmin[0][r], fmaf(-2.0f, acc0[r], Ej));
      runmin[1][r] = fminf(runmin[1][r], fmaf(-2.0f, acc1[r], Ej));
    }
  }
#pragma unroll
  for (int mt = 0; mt < 2; ++mt)
#pragma unroll
    for (int r = 0; r < 16; ++r) {
      float m = runmin[mt][r];
#pragma unroll
      for (int mask = 1; mask <= 16; mask <<= 1)
        m = fminf(m, __shfl_xor(m, mask, 64));
      if ((lane & 31) == 0) {
        int row = nbase + w * 64 + mt * 32 + (r & 3) + 8 * (r >> 2) + 4 * (lane >> 5);
        atomicMin(&rowmin_enc[row], encf(m));
      }
    }
}

__global__ __launch_bounds__(256, 2) void sweep1_kernel(
    const float* __restrict__ z, const short* __restrict__ ebuf,
    const float* __restrict__ E, const unsigned* __restrict__ rowmin_enc,
    int* __restrict__ cnt_g, int* __restrict__ cand_g) {
  __shared__ float4 btile[2][1024];
  const int t = threadIdx.x, w = t >> 6, lane = t & 63;
  const int rg = blockIdx.x >> 2, jq = blockIdx.x & 3;
  const int nbase = rg * 256;

  bf16x8 a[2][16];
  load_a_frags(z, nbase, w, lane, a);

  float thr[2][16];
#pragma unroll
  for (int mt = 0; mt < 2; ++mt)
#pragma unroll
    for (int r = 0; r < 16; ++r) {
      int row = nbase + w * 64 + mt * 32 + (r & 3) + 8 * (r >> 2) + 4 * (lane >> 5);
      thr[mt][r] = decf(rowmin_enc[row]) + RESCUE_W;
    }

  const float4* esrc = (const float4*)ebuf;
  const int jg0 = jq * 32;
  float4 pf[4];
#pragma unroll
  for (int q = 0; q < 4; ++q)
    btile[0][q * 256 + t] = esrc[(size_t)jg0 * 1024 + q * 256 + t];
#pragma unroll
  for (int q = 0; q < 4; ++q)
    pf[q] = esrc[(size_t)(jg0 + 1) * 1024 + q * 256 + t];

  for (int jt = 0; jt < 32; ++jt) {
    const int cur = jt & 1;
    __syncthreads();
    if (jt + 1 < 32) {
#pragma unroll
      for (int q = 0; q < 4; ++q) btile[cur ^ 1][q * 256 + t] = pf[q];
    }
    if (jt + 2 < 32) {
#pragma unroll
      for (int q = 0; q < 4; ++q)
        pf[q] = esrc[(size_t)(jg0 + jt + 2) * 1024 + q * 256 + t];
    }
    f32x16 acc0 = {0}, acc1 = {0};
    const bf16x8* bt = (const bf16x8*)btile[cur];
#pragma unroll
    for (int kf = 0; kf < 16; ++kf) {
      bf16x8 bf = bt[kf * 64 + lane];
      acc0 = __builtin_amdgcn_mfma_f32_32x32x16_bf16(a[0][kf], bf, acc0, 0, 0, 0);
      acc1 = __builtin_amdgcn_mfma_f32_32x32x16_bf16(a[1][kf], bf, acc1, 0, 0, 0);
    }
    const int jb = jq * 1024 + jt * 32;
    float Ej = E[jb + (lane & 31)];
    int jcol = jb + (lane & 31);
#pragma unroll
    for (int mt = 0; mt < 2; ++mt)
#pragma unroll
      for (int r = 0; r < 16; ++r) {
        float g = fmaf(-2.0f, (mt ? acc1[r] : acc0[r]), Ej);
        if (g <= thr[mt][r]) {
          int row = nbase + w * 64 + mt * 32 + (r & 3) + 8 * (r >> 2) + 4 * (lane >> 5);
          int slot = atomicAdd(&cnt_g[row], 1);
          if (slot < 8) cand_g[(size_t)row * 8 + slot] = jcol;
        }
      }
  }
}

// ---------- rescue: exact np-order chains over per-row candidates ----------
__global__ __launch_bounds__(256) void exact_cand_kernel(
    const float* __restrict__ z, const float* __restrict__ emb,
    const float* __restrict__ S, const float* __restrict__ E,
    const int* __restrict__ cnt_g, const int* __restrict__ cand_g,
    int* __restrict__ idx_out, float* __restrict__ idxf_out) {
  int row = blockIdx.x * 256 + threadIdx.x;
  int b = row >> 10, hw = row & 1023;
  const float* zr = z + (size_t)b * (DIM * HW_) + hw;   // z[k] at zr[k*1024]
  const float s = S[row];
  int c = cnt_g[row];
  float bd = 3.0e38f; int bj = 0x7fffffff;
  if (c <= 8) {
    for (int p = 0; p < c; ++p) {
      int j = cand_g[(size_t)row * 8 + p];
      const float* e = emb + (size_t)j * DIM;
      float acc = 0.0f;
#pragma unroll 8
      for (int k4 = 0; k4 < 64; ++k4) {          // sequential k ascending
        float4 ev = *(const float4*)(e + k4 * 4);
        acc = fmaf(zr[(size_t)(k4 * 4 + 0) * HW_], ev.x, acc);
        acc = fmaf(zr[(size_t)(k4 * 4 + 1) * HW_], ev.y, acc);
        acc = fmaf(zr[(size_t)(k4 * 4 + 2) * HW_], ev.z, acc);
        acc = fmaf(zr[(size_t)(k4 * 4 + 3) * HW_], ev.w, acc);
      }
      float d = fmaf(-2.0f, acc, s + E[j]);
      if (d < bd || (d == bd && j < bj)) { bd = d; bj = j; }
    }
  } else {
    for (int j = 0; j < KEMB; ++j) {             // overflow fallback (P~0)
      const float* e = emb + (size_t)j * DIM;
      float acc = 0.0f;
      for (int k4 = 0; k4 < 64; ++k4) {
        float4 ev = *(const float4*)(e + k4 * 4);
        acc = fmaf(zr[(size_t)(k4 * 4 + 0) * HW_], ev.x, acc);
        acc = fmaf(zr[(size_t)(k4 * 4 + 1) * HW_], ev.y, acc);
        acc = fmaf(zr[(size_t)(k4 * 4 + 2) * HW_], ev.z, acc);
        acc = fmaf(zr[(size_t)(k4 * 4 + 3) * HW_], ev.w, acc);
      }
      float d = fmaf(-2.0f, acc, s + E[j]);
      if (d < bd || (d == bd && j < bj)) { bd = d; bj = j; }
    }
  }
  idx_out[row] = bj;
  idxf_out[row] = (float)bj;
}

// ---------- fallback fp32 kernel (R2 version, known-passing) ----------
#define RT 64
#define JT 256
#define KC 16
__global__ __launch_bounds__(256, 2) void dist_argmin_kernel(
    const float* __restrict__ z, const float* __restrict__ emb,
    const float* __restrict__ S, const float* __restrict__ E,
    int* __restrict__ idx_out, float* __restrict__ idxf_out) {
  __shared__ float zt[DIM * RT];
  __shared__ float et[KC * JT];
  const int t  = threadIdx.x;
  const int g  = t & 31;
  const int tr = t >> 5;
  const int nb = blockIdx.x * RT;
  const int b  = nb >> 10;
  const int hwb = nb & 1023;
  const float* zb = z + (size_t)b * (DIM * HW_) + hwb;
#pragma unroll
  for (int i = 0; i < 16; ++i) {
    int flat = t + i * 256;
    int k  = flat >> 4;
    int r4 = flat & 15;
    float4 v = *(const float4*)(zb + (size_t)k * HW_ + r4 * 4);
    *(float4*)(zt + flat * 4) = v;
  }
  float bestd[8];
  int   bestj[8];
#pragma unroll
  for (int i = 0; i < 8; ++i) { bestd[i] = 3.0e38f; bestj[i] = 0; }
  float Sreg[8];
#pragma unroll
  for (int rr = 0; rr < 8; ++rr) Sreg[rr] = S[nb + tr * 8 + rr];
  float4 pf[4];
#pragma unroll
  for (int q = 0; q < 4; ++q) {
    int cid = q * 256 + t;
    pf[q] = *(const float4*)(emb + (size_t)(cid >> 2) * DIM + (cid & 3) * 4);
  }
  for (int jt = 0; jt < KEMB / JT; ++jt) {
    float acc[8][8];
#pragma unroll
    for (int rr = 0; rr < 8; ++rr)
#pragma unroll
      for (int c = 0; c < 8; ++c) acc[rr][c] = 0.0f;
    for (int kc = 0; kc < DIM / KC; ++kc) {
      __syncthreads();
#pragma unroll
      for (int q = 0; q < 4; ++q) {
        int cid = q * 256 + t;
        int j = cid >> 2, k4 = cid & 3;
        et[(k4 * 4 + 0) * JT + j] = pf[q].x;
        et[(k4 * 4 + 1) * JT + j] = pf[q].y;
        et[(k4 * 4 + 2) * JT + j] = pf[q].z;
        et[(k4 * 4 + 3) * JT + j] = pf[q].w;
      }
      int s = jt * (DIM / KC) + kc + 1;
      if (s < (KEMB / JT) * (DIM / KC)) {
        int njt = s >> 4, nkc = s & 15;
        const float* base = emb + (size_t)njt * JT * DIM + nkc * KC;
#pragma unroll
        for (int q = 0; q < 4; ++q) {
          int cid = q * 256 + t;
          pf[q] = *(const float4*)(base + (size_t)(cid >> 2) * DIM + (cid & 3) * 4);
        }
      }
      __syncthreads();
      const float* ztk = zt + (kc * KC) * RT;
#pragma unroll
      for (int kk = 0; kk < KC; ++kk) {
        float4 z0 = *(const float4*)(ztk + kk * RT + tr * 8);
        float4 z1 = *(const float4*)(ztk + kk * RT + tr * 8 + 4);
        float2 e0 = *(const float2*)(et + kk * JT + g * 2);
        float2 e1 = *(const float2*)(et + kk * JT + 64 + g * 2);
        float2 e2 = *(const float2*)(et + kk * JT + 128 + g * 2);
        float2 e3 = *(const float2*)(et + kk * JT + 192 + g * 2);
        float zr[8] = {z0.x, z0.y, z0.z, z0.w, z1.x, z1.y, z1.z, z1.w};
        float ev[8] = {e0.x, e0.y, e1.x, e1.y, e2.x, e2.y, e3.x, e3.y};
#pragma unroll
        for (int rr = 0; rr < 8; ++rr)
#pragma unroll
          for (int c = 0; c < 8; ++c)
            acc[rr][c] = fmaf(zr[rr], ev[c], acc[rr][c]);
      }
    }
    int jb = jt * JT;
    float Ereg[8];
#pragma unroll
    for (int c = 0; c < 8; ++c)
      Ereg[c] = E[jb + (c >> 1) * 64 + g * 2 + (c & 1)];
#pragma unroll
    for (int rr = 0; rr < 8; ++rr)
#pragma unroll
      for (int c = 0; c < 8; ++c) {
        float A = Sreg[rr] + Ereg[c];
        float d = fmaf(-2.0f, acc[rr][c], A);
        int j = jb + (c >> 1) * 64 + g * 2 + (c & 1);
        if (d < bestd[rr] || (d == bestd[rr] && j < bestj[rr])) {
          bestd[rr] = d; bestj[rr] = j;
        }
      }
  }
  __syncthreads();
  float* rd = et;
  int*   rj = (int*)(et + 2048);
#pragma unroll
  for (int rr = 0; rr < 8; ++rr) {
    rd[(tr * 8 + rr) * 32 + g] = bestd[rr];
    rj[(tr * 8 + rr) * 32 + g] = bestj[rr];
  }
  __syncthreads();
  if (t < RT) {
    float bd = rd[t * 32];
    int   bj = rj[t * 32];
    for (int c = 1; c < 32; ++c) {
      float d2 = rd[t * 32 + c];
      int   j2 = rj[t * 32 + c];
      if (d2 < bd || (d2 == bd && j2 < bj)) { bd = d2; bj = j2; }
    }
    idx_out[nb + t]  = bj;
    idxf_out[nb + t] = (float)bj;
  }
}

// ---------- epilogue: gather + STE + loss, fused finalize ----------
__global__ __launch_bounds__(256) void epilogue_kernel(
    const float* __restrict__ z, const float* __restrict__ emb,
    const int* __restrict__ idx, float* __restrict__ out0,
    double* __restrict__ loss_sum, int* __restrict__ done,
    float* __restrict__ out_loss) {
#pragma clang fp contract(off)
  __shared__ double wsum[4];
  double acc = 0.0;
#pragma unroll
  for (int it = 0; it < 4; ++it) {
    int u = (it * 2048 + blockIdx.x) * 256 + threadIdx.x;
    int gid = u * 4;
    int hw = gid & 1023;
    int d  = (gid >> 10) & 255;
    int b  = gid >> 18;
    int n  = b * 1024 + hw;
    float4 zp = *(const float4*)(z + gid);
    int4 iv = *(const int4*)(idx + n);
    float q0 = emb[(size_t)iv.x * DIM + d];
    float q1 = emb[(size_t)iv.y * DIM + d];
    float q2 = emb[(size_t)iv.z * DIM + d];
    float q3 = emb[(size_t)iv.w * DIM + d];
    float t0 = q0 - zp.x, t1 = q1 - zp.y, t2 = q2 - zp.z, t3 = q3 - zp.w;
    float4 o; o.x = zp.x + t0; o.y = zp.y + t1; o.z = zp.z + t2; o.w = zp.w + t3;
    *(float4*)(out0 + gid) = o;
    acc += (double)(t0 * t0);
    acc += (double)(t1 * t1);
    acc += (double)(t2 * t2);
    acc += (double)(t3 * t3);
  }
#pragma unroll
  for (int off = 32; off > 0; off >>= 1) acc += __shfl_down(acc, off, 64);
  int lane = threadIdx.x & 63, wv = threadIdx.x >> 6;
  if (lane == 0) wsum[wv] = acc;
  __syncthreads();
  if (threadIdx.x == 0) {
    double bsum = (wsum[0] + wsum[1]) + (wsum[2] + wsum[3]);
    atomicAdd(loss_sum, bsum);
    __threadfence();
    int prev = atomicAdd(done, 1);
    if (prev == 2047) {
      double m = loss_sum[0] / 8388608.0;
      float mf = (float)m;
      float bb = 10.0f * mf;
      out_loss[0] = mf + bb;
    }
  }
}

extern "C" void kernel_launch(void* const* d_in, const int* in_sizes, int n_in,
                              void* d_out, int out_size, void* d_ws, size_t ws_size,
                              hipStream_t stream) {
  const float* z   = (const float*)d_in[0];
  const float* emb = (const float*)d_in[1];
  float* out = (float*)d_out;
  char* ws = (char*)d_ws;
  int*      idx    = (int*)ws;
  float*    S      = (float*)(ws + WS_S_OFF);
  float*    E      = (float*)(ws + WS_E_OFF);
  double*   ls     = (double*)(ws + WS_LOSS_OFF);
  int*      done   = (int*)(ws + WS_DONE_OFF);
  int*      cnt    = (int*)(ws + WS_CNT_OFF);
  unsigned* rowmin = (unsigned*)(ws + WS_RMIN_OFF);
  int*      cand   = (int*)(ws + WS_CAND_OFF);
  short*    ebuf   = (short*)(ws + WS_EBUF_OFF);

  const int do_filter = (ws_size >= (size_t)WS_NEEDED) ? 1 : 0;

  prep_kernel<<<784, 256, 0, stream>>>(z, emb, S, E, ebuf, cnt, rowmin, ls,
                                       done, do_filter);

  if (do_filter) {
    sweep0_kernel<<<512, 256, 0, stream>>>(z, ebuf, E, rowmin);
    sweep1_kernel<<<512, 256, 0, stream>>>(z, ebuf, E, rowmin, cnt, cand);
    exact_cand_kernel<<<128, 256, 0, stream>>>(z, emb, S, E, cnt, cand, idx,
                                               out + 8388609);
  } else {
    dist_argmin_kernel<<<NROWS / RT, 256, 0, stream>>>(z, emb, S, E, idx,
                                                       out + 8388609);
  }

  epilogue_kernel<<<2048, 256, 0, stream>>>(z, emb, idx, out, ls, done,
                                            out + 8388608);
}

// Round 8
// 421.274 us; speedup vs baseline: 1.2436x; 1.2436x over previous
//
#include <hip/hip_runtime.h>

#define DIM   256
#define HW_   1024
#define NROWS 32768
#define KEMB  4096

// ---------------- ws layout ----------------
// [0,       131072)  int    idx[32768]
// [131072,  262144)  float  S[32768]
// [262144,  278528)  float  E[4096]
// [278528,  278536)  double loss_sum
// [278536,  278540)  int    done
// [278592,  409664)  int    cnt[32768]
// [540736,  1589312) int    cand[32768][8]
// [1589312, 3686464) short  ebuf[4096*512]  (bf16, 32x32-frag-major)
#define WS_S_OFF    131072
#define WS_E_OFF    262144
#define WS_LOSS_OFF 278528
#define WS_DONE_OFF 278536
#define WS_CNT_OFF  278592
#define WS_CAND_OFF 540736
#define WS_EBUF_OFF 1589312
#define WS_NEEDED   3686464
#define RESCUE_W    1.5e-4f

typedef __attribute__((ext_vector_type(8)))  short bf16x8;
typedef __attribute__((ext_vector_type(16))) float f32x16;

__device__ __forceinline__ unsigned short f2bf(float v) {
  unsigned u = __float_as_uint(v);
  return (unsigned short)((u + 0x7FFFu + ((u >> 16) & 1u)) >> 16);
}

// ---------- numpy-pairwise row sums of squares ----------
__device__ __forceinline__ float np_sumsq_128(const float* q, int stride) {
#pragma clang fp contract(off)
  float r[8];
#pragma unroll
  for (int i = 0; i < 8; ++i) { float v = q[i * stride]; r[i] = v * v; }
  for (int blk = 8; blk < 128; blk += 8) {
#pragma unroll
    for (int i = 0; i < 8; ++i) {
      float v = q[(blk + i) * stride];
      float sq = v * v;
      r[i] = r[i] + sq;
    }
  }
  return ((r[0] + r[1]) + (r[2] + r[3])) + ((r[4] + r[5]) + (r[6] + r[7]));
}

// ---------- prep: norms [0,144) + pack [144,656) ----------
// pack tile (jg, kf): lane l holds e[j = jg*32 + (l&31)][k = kf*16 + (l>>5)*8 + i]
// flat short offset = ((jg*16 + kf)*64 + l)*8  -> 16 KB contiguous per jg.
__global__ __launch_bounds__(256) void prep_kernel(
    const float* __restrict__ z, const float* __restrict__ emb,
    float* __restrict__ S, float* __restrict__ E, short* __restrict__ ebuf,
    double* __restrict__ loss_sum, int* __restrict__ done, int do_filter) {
#pragma clang fp contract(off)
  if (blockIdx.x < 144) {
    int t = blockIdx.x * 256 + threadIdx.x;
    if (t == 0) { loss_sum[0] = 0.0; done[0] = 0; }
    if (t < NROWS) {
      int b = t >> 10, hw = t & 1023;
      const float* p = z + (size_t)b * (DIM * HW_) + hw;
      float s0 = np_sumsq_128(p, HW_);
      float s1 = np_sumsq_128(p + 128 * HW_, HW_);
      S[t] = s0 + s1;
    } else if (t < NROWS + KEMB) {
      int j = t - NROWS;
      const float* p = emb + (size_t)j * DIM;
      float s0 = np_sumsq_128(p, 1);
      float s1 = np_sumsq_128(p + 128, 1);
      E[j] = s0 + s1;
    }
  } else {
    if (!do_filter) return;
    int u = (blockIdx.x - 144) * 256 + threadIdx.x;   // 0..131071
    int l = u & 63;
    int kf = (u >> 6) & 15;
    int jg = u >> 10;
    int j = jg * 32 + (l & 31);
    int kb = kf * 16 + (l >> 5) * 8;
    const float* p = emb + (size_t)j * DIM + kb;
    short out[8];
#pragma unroll
    for (int i = 0; i < 8; ++i) out[i] = (short)f2bf(p[i]);
    *(bf16x8*)(ebuf + (size_t)u * 8) = *(bf16x8*)out;
  }
}

// ---------- fused filter: two-sweep 32x32x16 MFMA, B direct from global ----------
// Grid 512 x 256 thr (4 waves). Block = 64 rows (z/A loaded once, shared
// layout by all waves); wave w = j-quarter [w*1024, +1024) as 32 groups of
// 32 j. A resident: a[2][16] bf16x8 (128 VGPR). B-frags (1 KB each) read
// straight from ebuf (L2-hot, 2 MB); 16 loads hoisted per group by the
// compiler under the (256,2) register budget. Sweep 0: block-local row
// minima via LDS. Sweep 1: identical recompute, emit j where g <= min + W.
// A/B lane = [dim: l&31][k: (l>>5)*8+i]; C/D row = (r&3)+8*(r>>2)+4*(l>>5),
// col = l&31  [R6/R7 HW-verified, absmax 0].
__global__ __launch_bounds__(256, 2) void filter_kernel(
    const float* __restrict__ z, const short* __restrict__ ebuf,
    const float* __restrict__ E, int* __restrict__ cnt_g,
    int* __restrict__ cand_g) {
  __shared__ float rowmin_l[64][4];
  __shared__ float thr_l[64];
  __shared__ int   cnt_l[64];
  __shared__ int   cand_l[64][8];

  const int t = threadIdx.x, w = t >> 6, lane = t & 63;
  const int nb = blockIdx.x * 64;
  const int b = nb >> 10, hwb = nb & 1023;   // 64 | 1024: no b straddle

  // ---- one-time A load + bf16 convert (64 rows, 2 m-tiles of 32) ----
  bf16x8 a[2][16];
  {
    const float* zw = z + (size_t)b * (DIM * HW_) + hwb + (lane & 31);
#pragma unroll
    for (int mt = 0; mt < 2; ++mt) {
#pragma unroll
      for (int kf = 0; kf < 16; ++kf) {
        short tmp[8];
#pragma unroll
        for (int i = 0; i < 8; ++i) {
          int k = kf * 16 + (lane >> 5) * 8 + i;
          tmp[i] = (short)f2bf(zw[mt * 32 + (size_t)k * HW_]);
        }
        a[mt][kf] = *(bf16x8*)tmp;
      }
    }
  }

  const int jg0 = w * 32;                     // wave's 32 j-groups
  const bf16x8* ebase = (const bf16x8*)ebuf;

  // ================= sweep 0: row minima =================
  float runmin[2][16];
#pragma unroll
  for (int mt = 0; mt < 2; ++mt)
#pragma unroll
    for (int r = 0; r < 16; ++r) runmin[mt][r] = 3.0e38f;

  for (int g = 0; g < 32; ++g) {
    const int jg = jg0 + g;
    const bf16x8* bp = ebase + (size_t)jg * 1024 + lane;
    f32x16 acc0 = {0}, acc1 = {0};
#pragma unroll
    for (int kf = 0; kf < 16; ++kf) {
      bf16x8 bf = bp[kf * 64];
      acc0 = __builtin_amdgcn_mfma_f32_32x32x16_bf16(a[0][kf], bf, acc0, 0, 0, 0);
      acc1 = __builtin_amdgcn_mfma_f32_32x32x16_bf16(a[1][kf], bf, acc1, 0, 0, 0);
    }
    float Ej = E[jg * 32 + (lane & 31)];
#pragma unroll
    for (int r = 0; r < 16; ++r) {
      runmin[0][r] = fminf(runmin[0][r], fmaf(-2.0f, acc0[r], Ej));
      runmin[1][r] = fminf(runmin[1][r], fmaf(-2.0f, acc1[r], Ej));
    }
  }
  // reduce over the 32 j-columns (masks 1..16 stay within each 32-lane half)
#pragma unroll
  for (int mt = 0; mt < 2; ++mt)
#pragma unroll
    for (int r = 0; r < 16; ++r) {
      float m = runmin[mt][r];
#pragma unroll
      for (int mask = 1; mask <= 16; mask <<= 1)
        m = fminf(m, __shfl_xor(m, mask, 64));
      if ((lane & 31) == 0) {
        int rl = mt * 32 + (r & 3) + 8 * (r >> 2) + 4 * (lane >> 5);
        rowmin_l[rl][w] = m;
      }
    }
  __syncthreads();
  if (t < 64) {
    float m = fminf(fminf(rowmin_l[t][0], rowmin_l[t][1]),
                    fminf(rowmin_l[t][2], rowmin_l[t][3]));
    thr_l[t] = m + RESCUE_W;
    cnt_l[t] = 0;
  }
  __syncthreads();
  float thr[2][16];
#pragma unroll
  for (int mt = 0; mt < 2; ++mt)
#pragma unroll
    for (int r = 0; r < 16; ++r)
      thr[mt][r] = thr_l[mt * 32 + (r & 3) + 8 * (r >> 2) + 4 * (lane >> 5)];

  // ================= sweep 1: identical recompute + emission =================
  for (int g = 0; g < 32; ++g) {
    const int jg = jg0 + g;
    const bf16x8* bp = ebase + (size_t)jg * 1024 + lane;
    f32x16 acc0 = {0}, acc1 = {0};
#pragma unroll
    for (int kf = 0; kf < 16; ++kf) {
      bf16x8 bf = bp[kf * 64];
      acc0 = __builtin_amdgcn_mfma_f32_32x32x16_bf16(a[0][kf], bf, acc0, 0, 0, 0);
      acc1 = __builtin_amdgcn_mfma_f32_32x32x16_bf16(a[1][kf], bf, acc1, 0, 0, 0);
    }
    int jcol = jg * 32 + (lane & 31);
    float Ej = E[jcol];
#pragma unroll
    for (int mt = 0; mt < 2; ++mt)
#pragma unroll
      for (int r = 0; r < 16; ++r) {
        float gv = fmaf(-2.0f, (mt ? acc1[r] : acc0[r]), Ej);
        if (gv <= thr[mt][r]) {
          int rl = mt * 32 + (r & 3) + 8 * (r >> 2) + 4 * (lane >> 5);
          int slot = atomicAdd(&cnt_l[rl], 1);
          if (slot < 8) cand_l[rl][slot] = jcol;
        }
      }
  }
  __syncthreads();
  if (t < 64) {
    int c = cnt_l[t];
    cnt_g[nb + t] = c;
    int cc = c > 8 ? 8 : c;
    for (int p = 0; p < cc; ++p) cand_g[(size_t)(nb + t) * 8 + p] = cand_l[t][p];
  }
}

// ---------- rescue: exact np-order chains over per-row candidates ----------
__global__ __launch_bounds__(256) void exact_cand_kernel(
    const float* __restrict__ z, const float* __restrict__ emb,
    const float* __restrict__ S, const float* __restrict__ E,
    const int* __restrict__ cnt_g, const int* __restrict__ cand_g,
    int* __restrict__ idx_out, float* __restrict__ idxf_out) {
  int row = blockIdx.x * 256 + threadIdx.x;
  int b = row >> 10, hw = row & 1023;
  const float* zr = z + (size_t)b * (DIM * HW_) + hw;   // z[k] at zr[k*1024]
  const float s = S[row];
  int c = cnt_g[row];
  float bd = 3.0e38f; int bj = 0x7fffffff;
  if (c <= 8) {
    for (int p = 0; p < c; ++p) {
      int j = cand_g[(size_t)row * 8 + p];
      const float* e = emb + (size_t)j * DIM;
      float acc = 0.0f;
#pragma unroll 8
      for (int k4 = 0; k4 < 64; ++k4) {          // sequential k ascending
        float4 ev = *(const float4*)(e + k4 * 4);
        acc = fmaf(zr[(size_t)(k4 * 4 + 0) * HW_], ev.x, acc);
        acc = fmaf(zr[(size_t)(k4 * 4 + 1) * HW_], ev.y, acc);
        acc = fmaf(zr[(size_t)(k4 * 4 + 2) * HW_], ev.z, acc);
        acc = fmaf(zr[(size_t)(k4 * 4 + 3) * HW_], ev.w, acc);
      }
      float d = fmaf(-2.0f, acc, s + E[j]);
      if (d < bd || (d == bd && j < bj)) { bd = d; bj = j; }
    }
  } else {
    for (int j = 0; j < KEMB; ++j) {             // overflow fallback (P~0)
      const float* e = emb + (size_t)j * DIM;
      float acc = 0.0f;
      for (int k4 = 0; k4 < 64; ++k4) {
        float4 ev = *(const float4*)(e + k4 * 4);
        acc = fmaf(zr[(size_t)(k4 * 4 + 0) * HW_], ev.x, acc);
        acc = fmaf(zr[(size_t)(k4 * 4 + 1) * HW_], ev.y, acc);
        acc = fmaf(zr[(size_t)(k4 * 4 + 2) * HW_], ev.z, acc);
        acc = fmaf(zr[(size_t)(k4 * 4 + 3) * HW_], ev.w, acc);
      }
      float d = fmaf(-2.0f, acc, s + E[j]);
      if (d < bd || (d == bd && j < bj)) { bd = d; bj = j; }
    }
  }
  idx_out[row] = bj;
  idxf_out[row] = (float)bj;
}

// ---------- fallback fp32 kernel (R2 version, known-passing) ----------
#define RT 64
#define JT 256
#define KC 16
__global__ __launch_bounds__(256, 2) void dist_argmin_kernel(
    const float* __restrict__ z, const float* __restrict__ emb,
    const float* __restrict__ S, const float* __restrict__ E,
    int* __restrict__ idx_out, float* __restrict__ idxf_out) {
  __shared__ float zt[DIM * RT];
  __shared__ float et[KC * JT];
  const int t  = threadIdx.x;
  const int g  = t & 31;
  const int tr = t >> 5;
  const int nb = blockIdx.x * RT;
  const int b  = nb >> 10;
  const int hwb = nb & 1023;
  const float* zb = z + (size_t)b * (DIM * HW_) + hwb;
#pragma unroll
  for (int i = 0; i < 16; ++i) {
    int flat = t + i * 256;
    int k  = flat >> 4;
    int r4 = flat & 15;
    float4 v = *(const float4*)(zb + (size_t)k * HW_ + r4 * 4);
    *(float4*)(zt + flat * 4) = v;
  }
  float bestd[8];
  int   bestj[8];
#pragma unroll
  for (int i = 0; i < 8; ++i) { bestd[i] = 3.0e38f; bestj[i] = 0; }
  float Sreg[8];
#pragma unroll
  for (int rr = 0; rr < 8; ++rr) Sreg[rr] = S[nb + tr * 8 + rr];
  float4 pf[4];
#pragma unroll
  for (int q = 0; q < 4; ++q) {
    int cid = q * 256 + t;
    pf[q] = *(const float4*)(emb + (size_t)(cid >> 2) * DIM + (cid & 3) * 4);
  }
  for (int jt = 0; jt < KEMB / JT; ++jt) {
    float acc[8][8];
#pragma unroll
    for (int rr = 0; rr < 8; ++rr)
#pragma unroll
      for (int c = 0; c < 8; ++c) acc[rr][c] = 0.0f;
    for (int kc = 0; kc < DIM / KC; ++kc) {
      __syncthreads();
#pragma unroll
      for (int q = 0; q < 4; ++q) {
        int cid = q * 256 + t;
        int j = cid >> 2, k4 = cid & 3;
        et[(k4 * 4 + 0) * JT + j] = pf[q].x;
        et[(k4 * 4 + 1) * JT + j] = pf[q].y;
        et[(k4 * 4 + 2) * JT + j] = pf[q].z;
        et[(k4 * 4 + 3) * JT + j] = pf[q].w;
      }
      int s = jt * (DIM / KC) + kc + 1;
      if (s < (KEMB / JT) * (DIM / KC)) {
        int njt = s >> 4, nkc = s & 15;
        const float* base = emb + (size_t)njt * JT * DIM + nkc * KC;
#pragma unroll
        for (int q = 0; q < 4; ++q) {
          int cid = q * 256 + t;
          pf[q] = *(const float4*)(base + (size_t)(cid >> 2) * DIM + (cid & 3) * 4);
        }
      }
      __syncthreads();
      const float* ztk = zt + (kc * KC) * RT;
#pragma unroll
      for (int kk = 0; kk < KC; ++kk) {
        float4 z0 = *(const float4*)(ztk + kk * RT + tr * 8);
        float4 z1 = *(const float4*)(ztk + kk * RT + tr * 8 + 4);
        float2 e0 = *(const float2*)(et + kk * JT + g * 2);
        float2 e1 = *(const float2*)(et + kk * JT + 64 + g * 2);
        float2 e2 = *(const float2*)(et + kk * JT + 128 + g * 2);
        float2 e3 = *(const float2*)(et + kk * JT + 192 + g * 2);
        float zr[8] = {z0.x, z0.y, z0.z, z0.w, z1.x, z1.y, z1.z, z1.w};
        float ev[8] = {e0.x, e0.y, e1.x, e1.y, e2.x, e2.y, e3.x, e3.y};
#pragma unroll
        for (int rr = 0; rr < 8; ++rr)
#pragma unroll
          for (int c = 0; c < 8; ++c)
            acc[rr][c] = fmaf(zr[rr], ev[c], acc[rr][c]);
      }
    }
    int jb = jt * JT;
    float Ereg[8];
#pragma unroll
    for (int c = 0; c < 8; ++c)
      Ereg[c] = E[jb + (c >> 1) * 64 + g * 2 + (c & 1)];
#pragma unroll
    for (int rr = 0; rr < 8; ++rr)
#pragma unroll
      for (int c = 0; c < 8; ++c) {
        float A = Sreg[rr] + Ereg[c];
        float d = fmaf(-2.0f, acc[rr][c], A);
        int j = jb + (c >> 1) * 64 + g * 2 + (c & 1);
        if (d < bestd[rr] || (d == bestd[rr] && j < bestj[rr])) {
          bestd[rr] = d; bestj[rr] = j;
        }
      }
  }
  __syncthreads();
  float* rd = et;
  int*   rj = (int*)(et + 2048);
#pragma unroll
  for (int rr = 0; rr < 8; ++rr) {
    rd[(tr * 8 + rr) * 32 + g] = bestd[rr];
    rj[(tr * 8 + rr) * 32 + g] = bestj[rr];
  }
  __syncthreads();
  if (t < RT) {
    float bd = rd[t * 32];
    int   bj = rj[t * 32];
    for (int c = 1; c < 32; ++c) {
      float d2 = rd[t * 32 + c];
      int   j2 = rj[t * 32 + c];
      if (d2 < bd || (d2 == bd && j2 < bj)) { bd = d2; bj = j2; }
    }
    idx_out[nb + t]  = bj;
    idxf_out[nb + t] = (float)bj;
  }
}

// ---------- epilogue: gather + STE + loss, fused finalize ----------
__global__ __launch_bounds__(256) void epilogue_kernel(
    const float* __restrict__ z, const float* __restrict__ emb,
    const int* __restrict__ idx, float* __restrict__ out0,
    double* __restrict__ loss_sum, int* __restrict__ done,
    float* __restrict__ out_loss) {
#pragma clang fp contract(off)
  __shared__ double wsum[4];
  double acc = 0.0;
#pragma unroll
  for (int it = 0; it < 4; ++it) {
    int u = (it * 2048 + blockIdx.x) * 256 + threadIdx.x;
    int gid = u * 4;
    int hw = gid & 1023;
    int d  = (gid >> 10) & 255;
    int b  = gid >> 18;
    int n  = b * 1024 + hw;
    float4 zp = *(const float4*)(z + gid);
    int4 iv = *(const int4*)(idx + n);
    float q0 = emb[(size_t)iv.x * DIM + d];
    float q1 = emb[(size_t)iv.y * DIM + d];
    float q2 = emb[(size_t)iv.z * DIM + d];
    float q3 = emb[(size_t)iv.w * DIM + d];
    float t0 = q0 - zp.x, t1 = q1 - zp.y, t2 = q2 - zp.z, t3 = q3 - zp.w;
    float4 o; o.x = zp.x + t0; o.y = zp.y + t1; o.z = zp.z + t2; o.w = zp.w + t3;
    *(float4*)(out0 + gid) = o;
    acc += (double)(t0 * t0);
    acc += (double)(t1 * t1);
    acc += (double)(t2 * t2);
    acc += (double)(t3 * t3);
  }
#pragma unroll
  for (int off = 32; off > 0; off >>= 1) acc += __shfl_down(acc, off, 64);
  int lane = threadIdx.x & 63, wv = threadIdx.x >> 6;
  if (lane == 0) wsum[wv] = acc;
  __syncthreads();
  if (threadIdx.x == 0) {
    double bsum = (wsum[0] + wsum[1]) + (wsum[2] + wsum[3]);
    atomicAdd(loss_sum, bsum);
    __threadfence();
    int prev = atomicAdd(done, 1);
    if (prev == 2047) {
      double m = loss_sum[0] / 8388608.0;
      float mf = (float)m;
      float bb = 10.0f * mf;
      out_loss[0] = mf + bb;
    }
  }
}

extern "C" void kernel_launch(void* const* d_in, const int* in_sizes, int n_in,
                              void* d_out, int out_size, void* d_ws, size_t ws_size,
                              hipStream_t stream) {
  const float* z   = (const float*)d_in[0];
  const float* emb = (const float*)d_in[1];
  float* out = (float*)d_out;
  char* ws = (char*)d_ws;
  int*      idx  = (int*)ws;
  float*    S    = (float*)(ws + WS_S_OFF);
  float*    E    = (float*)(ws + WS_E_OFF);
  double*   ls   = (double*)(ws + WS_LOSS_OFF);
  int*      done = (int*)(ws + WS_DONE_OFF);
  int*      cnt  = (int*)(ws + WS_CNT_OFF);
  int*      cand = (int*)(ws + WS_CAND_OFF);
  short*    ebuf = (short*)(ws + WS_EBUF_OFF);

  const int do_filter = (ws_size >= (size_t)WS_NEEDED) ? 1 : 0;

  prep_kernel<<<656, 256, 0, stream>>>(z, emb, S, E, ebuf, ls, done, do_filter);

  if (do_filter) {
    filter_kernel<<<512, 256, 0, stream>>>(z, ebuf, E, cnt, cand);
    exact_cand_kernel<<<128, 256, 0, stream>>>(z, emb, S, E, cnt, cand, idx,
                                               out + 8388609);
  } else {
    dist_argmin_kernel<<<NROWS / RT, 256, 0, stream>>>(z, emb, S, E, idx,
                                                       out + 8388609);
  }

  epilogue_kernel<<<2048, 256, 0, stream>>>(z, emb, idx, out, ls, done,
                                            out + 8388608);
}

// Round 9
// 418.637 us; speedup vs baseline: 1.2514x; 1.0063x over previous
//
#include <hip/hip_runtime.h>

#define DIM   256
#define HW_   1024
#define NROWS 32768
#define KEMB  4096

// ---------------- ws layout ----------------
// [0,       131072)  int    idx[32768]
// [131072,  262144)  float  S[32768]
// [262144,  278528)  float  E[4096]
// [278528,  278536)  double loss_sum
// [278536,  278540)  int    done
// [278592,  409664)  int    cnt[32768]
// [540736,  1589312) int    cand[32768][8]
// [1589312, 3686464) short  ebuf[4096*512]  (bf16, 32x32-frag-major)
#define WS_S_OFF    131072
#define WS_E_OFF    262144
#define WS_LOSS_OFF 278528
#define WS_DONE_OFF 278536
#define WS_CNT_OFF  278592
#define WS_CAND_OFF 540736
#define WS_EBUF_OFF 1589312
#define WS_NEEDED   3686464
#define RESCUE_W    1.5e-4f

typedef __attribute__((ext_vector_type(8)))  short bf16x8;
typedef __attribute__((ext_vector_type(16))) float f32x16;

__device__ __forceinline__ unsigned short f2bf(float v) {
  unsigned u = __float_as_uint(v);
  return (unsigned short)((u + 0x7FFFu + ((u >> 16) & 1u)) >> 16);
}

// ---------- numpy-pairwise row sums of squares ----------
__device__ __forceinline__ float np_sumsq_128(const float* q, int stride) {
#pragma clang fp contract(off)
  float r[8];
#pragma unroll
  for (int i = 0; i < 8; ++i) { float v = q[i * stride]; r[i] = v * v; }
  for (int blk = 8; blk < 128; blk += 8) {
#pragma unroll
    for (int i = 0; i < 8; ++i) {
      float v = q[(blk + i) * stride];
      float sq = v * v;
      r[i] = r[i] + sq;
    }
  }
  return ((r[0] + r[1]) + (r[2] + r[3])) + ((r[4] + r[5]) + (r[6] + r[7]));
}

// ---------- prep: norms [0,144) + pack [144,656) ----------
// pack tile (jg, kf): lane l holds e[j = jg*32 + (l&31)][k = kf*16 + (l>>5)*8 + i]
// flat short offset = ((jg*16 + kf)*64 + l)*8  -> 16 KB contiguous per jg.
__global__ __launch_bounds__(256) void prep_kernel(
    const float* __restrict__ z, const float* __restrict__ emb,
    float* __restrict__ S, float* __restrict__ E, short* __restrict__ ebuf,
    double* __restrict__ loss_sum, int* __restrict__ done, int do_filter) {
#pragma clang fp contract(off)
  if (blockIdx.x < 144) {
    int t = blockIdx.x * 256 + threadIdx.x;
    if (t == 0) { loss_sum[0] = 0.0; done[0] = 0; }
    if (t < NROWS) {
      int b = t >> 10, hw = t & 1023;
      const float* p = z + (size_t)b * (DIM * HW_) + hw;
      float s0 = np_sumsq_128(p, HW_);
      float s1 = np_sumsq_128(p + 128 * HW_, HW_);
      S[t] = s0 + s1;
    } else if (t < NROWS + KEMB) {
      int j = t - NROWS;
      const float* p = emb + (size_t)j * DIM;
      float s0 = np_sumsq_128(p, 1);
      float s1 = np_sumsq_128(p + 128, 1);
      E[j] = s0 + s1;
    }
  } else {
    if (!do_filter) return;
    int u = (blockIdx.x - 144) * 256 + threadIdx.x;   // 0..131071
    int l = u & 63;
    int kf = (u >> 6) & 15;
    int jg = u >> 10;
    int j = jg * 32 + (l & 31);
    int kb = kf * 16 + (l >> 5) * 8;
    const float* p = emb + (size_t)j * DIM + kb;
    short out[8];
#pragma unroll
    for (int i = 0; i < 8; ++i) out[i] = (short)f2bf(p[i]);
    *(bf16x8*)(ebuf + (size_t)u * 8) = *(bf16x8*)out;
  }
}

// ---------- fused filter: two-sweep 32x32x16 MFMA, B direct from L2 ----------
// Grid 512 x 256 thr (4 waves). Block = 64 rows (A loaded once per wave);
// wave w = j-quarter [w*1024, +1024) as 16 iterations x 2 j-groups of 32.
// 4 independent MFMA chains of 16 per iteration (2 groups x 2 m-tiles) give
// the ILP the R8 2-chain version lacked; B loads interleave per-kf.
// A/B lane = [dim: l&31][k: (l>>5)*8+i]; C/D row = (r&3)+8*(r>>2)+4*(l>>5),
// col = l&31  [R6-R8 HW-verified, absmax 0]. Per-(row,j) numerics identical
// to R8 (same chain sequence) -> same g, same emissions.
__global__ __launch_bounds__(256, 2) void filter_kernel(
    const float* __restrict__ z, const short* __restrict__ ebuf,
    const float* __restrict__ E, int* __restrict__ cnt_g,
    int* __restrict__ cand_g) {
  __shared__ float rowmin_l[64][4];
  __shared__ float thr_l[64];
  __shared__ int   cnt_l[64];
  __shared__ int   cand_l[64][8];

  const int t = threadIdx.x, w = t >> 6, lane = t & 63;
  const int nb = blockIdx.x * 64;
  const int b = nb >> 10, hwb = nb & 1023;   // 64 | 1024: no b straddle

  // ---- one-time A load + bf16 convert (64 rows, 2 m-tiles of 32) ----
  bf16x8 a[2][16];
  {
    const float* zw = z + (size_t)b * (DIM * HW_) + hwb + (lane & 31);
#pragma unroll
    for (int mt = 0; mt < 2; ++mt) {
#pragma unroll
      for (int kf = 0; kf < 16; ++kf) {
        short tmp[8];
#pragma unroll
        for (int i = 0; i < 8; ++i) {
          int k = kf * 16 + (lane >> 5) * 8 + i;
          tmp[i] = (short)f2bf(zw[mt * 32 + (size_t)k * HW_]);
        }
        a[mt][kf] = *(bf16x8*)tmp;
      }
    }
  }

  const int jg0 = w * 32;                     // wave's 32 j-groups
  const bf16x8* ebase = (const bf16x8*)ebuf;

  // ================= sweep 0: row minima =================
  float runmin[2][16];
#pragma unroll
  for (int mt = 0; mt < 2; ++mt)
#pragma unroll
    for (int r = 0; r < 16; ++r) runmin[mt][r] = 3.0e38f;

  for (int it = 0; it < 16; ++it) {
    const int jga = jg0 + it * 2;
    const bf16x8* bpa = ebase + (size_t)jga * 1024 + lane;
    const bf16x8* bpb = bpa + 1024;
    f32x16 accA0 = {0}, accA1 = {0}, accB0 = {0}, accB1 = {0};
#pragma unroll
    for (int kf = 0; kf < 16; ++kf) {
      bf16x8 bfa = bpa[kf * 64];
      bf16x8 bfb = bpb[kf * 64];
      accA0 = __builtin_amdgcn_mfma_f32_32x32x16_bf16(a[0][kf], bfa, accA0, 0, 0, 0);
      accA1 = __builtin_amdgcn_mfma_f32_32x32x16_bf16(a[1][kf], bfa, accA1, 0, 0, 0);
      accB0 = __builtin_amdgcn_mfma_f32_32x32x16_bf16(a[0][kf], bfb, accB0, 0, 0, 0);
      accB1 = __builtin_amdgcn_mfma_f32_32x32x16_bf16(a[1][kf], bfb, accB1, 0, 0, 0);
    }
    float Eja = E[jga * 32 + (lane & 31)];
    float Ejb = E[jga * 32 + 32 + (lane & 31)];
#pragma unroll
    for (int r = 0; r < 16; ++r) {
      runmin[0][r] = fminf(runmin[0][r], fmaf(-2.0f, accA0[r], Eja));
      runmin[1][r] = fminf(runmin[1][r], fmaf(-2.0f, accA1[r], Eja));
      runmin[0][r] = fminf(runmin[0][r], fmaf(-2.0f, accB0[r], Ejb));
      runmin[1][r] = fminf(runmin[1][r], fmaf(-2.0f, accB1[r], Ejb));
    }
  }
  // reduce over the 32 j-columns (masks 1..16 stay within each 32-lane half)
#pragma unroll
  for (int mt = 0; mt < 2; ++mt)
#pragma unroll
    for (int r = 0; r < 16; ++r) {
      float m = runmin[mt][r];
#pragma unroll
      for (int mask = 1; mask <= 16; mask <<= 1)
        m = fminf(m, __shfl_xor(m, mask, 64));
      if ((lane & 31) == 0) {
        int rl = mt * 32 + (r & 3) + 8 * (r >> 2) + 4 * (lane >> 5);
        rowmin_l[rl][w] = m;
      }
    }
  __syncthreads();
  if (t < 64) {
    float m = fminf(fminf(rowmin_l[t][0], rowmin_l[t][1]),
                    fminf(rowmin_l[t][2], rowmin_l[t][3]));
    thr_l[t] = m + RESCUE_W;
    cnt_l[t] = 0;
  }
  __syncthreads();
  float thr[2][16];
#pragma unroll
  for (int mt = 0; mt < 2; ++mt)
#pragma unroll
    for (int r = 0; r < 16; ++r)
      thr[mt][r] = thr_l[mt * 32 + (r & 3) + 8 * (r >> 2) + 4 * (lane >> 5)];

  // ================= sweep 1: identical recompute + emission =================
  for (int it = 0; it < 16; ++it) {
    const int jga = jg0 + it * 2;
    const bf16x8* bpa = ebase + (size_t)jga * 1024 + lane;
    const bf16x8* bpb = bpa + 1024;
    f32x16 accA0 = {0}, accA1 = {0}, accB0 = {0}, accB1 = {0};
#pragma unroll
    for (int kf = 0; kf < 16; ++kf) {
      bf16x8 bfa = bpa[kf * 64];
      bf16x8 bfb = bpb[kf * 64];
      accA0 = __builtin_amdgcn_mfma_f32_32x32x16_bf16(a[0][kf], bfa, accA0, 0, 0, 0);
      accA1 = __builtin_amdgcn_mfma_f32_32x32x16_bf16(a[1][kf], bfa, accA1, 0, 0, 0);
      accB0 = __builtin_amdgcn_mfma_f32_32x32x16_bf16(a[0][kf], bfb, accB0, 0, 0, 0);
      accB1 = __builtin_amdgcn_mfma_f32_32x32x16_bf16(a[1][kf], bfb, accB1, 0, 0, 0);
    }
    int jca = jga * 32 + (lane & 31);
    int jcb = jca + 32;
    float Eja = E[jca];
    float Ejb = E[jcb];
#pragma unroll
    for (int mt = 0; mt < 2; ++mt)
#pragma unroll
      for (int r = 0; r < 16; ++r) {
        float ga = fmaf(-2.0f, (mt ? accA1[r] : accA0[r]), Eja);
        float gb = fmaf(-2.0f, (mt ? accB1[r] : accB0[r]), Ejb);
        if (ga <= thr[mt][r]) {
          int rl = mt * 32 + (r & 3) + 8 * (r >> 2) + 4 * (lane >> 5);
          int slot = atomicAdd(&cnt_l[rl], 1);
          if (slot < 8) cand_l[rl][slot] = jca;
        }
        if (gb <= thr[mt][r]) {
          int rl = mt * 32 + (r & 3) + 8 * (r >> 2) + 4 * (lane >> 5);
          int slot = atomicAdd(&cnt_l[rl], 1);
          if (slot < 8) cand_l[rl][slot] = jcb;
        }
      }
  }
  __syncthreads();
  if (t < 64) {
    int c = cnt_l[t];
    cnt_g[nb + t] = c;
    int cc = c > 8 ? 8 : c;
    for (int p = 0; p < cc; ++p) cand_g[(size_t)(nb + t) * 8 + p] = cand_l[t][p];
  }
}

// ---------- rescue: exact np-order chains over per-row candidates ----------
__global__ __launch_bounds__(256) void exact_cand_kernel(
    const float* __restrict__ z, const float* __restrict__ emb,
    const float* __restrict__ S, const float* __restrict__ E,
    const int* __restrict__ cnt_g, const int* __restrict__ cand_g,
    int* __restrict__ idx_out, float* __restrict__ idxf_out) {
  int row = blockIdx.x * 256 + threadIdx.x;
  int b = row >> 10, hw = row & 1023;
  const float* zr = z + (size_t)b * (DIM * HW_) + hw;   // z[k] at zr[k*1024]
  const float s = S[row];
  int c = cnt_g[row];
  float bd = 3.0e38f; int bj = 0x7fffffff;
  if (c <= 8) {
    for (int p = 0; p < c; ++p) {
      int j = cand_g[(size_t)row * 8 + p];
      const float* e = emb + (size_t)j * DIM;
      float acc = 0.0f;
#pragma unroll 8
      for (int k4 = 0; k4 < 64; ++k4) {          // sequential k ascending
        float4 ev = *(const float4*)(e + k4 * 4);
        acc = fmaf(zr[(size_t)(k4 * 4 + 0) * HW_], ev.x, acc);
        acc = fmaf(zr[(size_t)(k4 * 4 + 1) * HW_], ev.y, acc);
        acc = fmaf(zr[(size_t)(k4 * 4 + 2) * HW_], ev.z, acc);
        acc = fmaf(zr[(size_t)(k4 * 4 + 3) * HW_], ev.w, acc);
      }
      float d = fmaf(-2.0f, acc, s + E[j]);
      if (d < bd || (d == bd && j < bj)) { bd = d; bj = j; }
    }
  } else {
    for (int j = 0; j < KEMB; ++j) {             // overflow fallback (P~0)
      const float* e = emb + (size_t)j * DIM;
      float acc = 0.0f;
      for (int k4 = 0; k4 < 64; ++k4) {
        float4 ev = *(const float4*)(e + k4 * 4);
        acc = fmaf(zr[(size_t)(k4 * 4 + 0) * HW_], ev.x, acc);
        acc = fmaf(zr[(size_t)(k4 * 4 + 1) * HW_], ev.y, acc);
        acc = fmaf(zr[(size_t)(k4 * 4 + 2) * HW_], ev.z, acc);
        acc = fmaf(zr[(size_t)(k4 * 4 + 3) * HW_], ev.w, acc);
      }
      float d = fmaf(-2.0f, acc, s + E[j]);
      if (d < bd || (d == bd && j < bj)) { bd = d; bj = j; }
    }
  }
  idx_out[row] = bj;
  idxf_out[row] = (float)bj;
}

// ---------- fallback fp32 kernel (R2 version, known-passing) ----------
#define RT 64
#define JT 256
#define KC 16
__global__ __launch_bounds__(256, 2) void dist_argmin_kernel(
    const float* __restrict__ z, const float* __restrict__ emb,
    const float* __restrict__ S, const float* __restrict__ E,
    int* __restrict__ idx_out, float* __restrict__ idxf_out) {
  __shared__ float zt[DIM * RT];
  __shared__ float et[KC * JT];
  const int t  = threadIdx.x;
  const int g  = t & 31;
  const int tr = t >> 5;
  const int nb = blockIdx.x * RT;
  const int b  = nb >> 10;
  const int hwb = nb & 1023;
  const float* zb = z + (size_t)b * (DIM * HW_) + hwb;
#pragma unroll
  for (int i = 0; i < 16; ++i) {
    int flat = t + i * 256;
    int k  = flat >> 4;
    int r4 = flat & 15;
    float4 v = *(const float4*)(zb + (size_t)k * HW_ + r4 * 4);
    *(float4*)(zt + flat * 4) = v;
  }
  float bestd[8];
  int   bestj[8];
#pragma unroll
  for (int i = 0; i < 8; ++i) { bestd[i] = 3.0e38f; bestj[i] = 0; }
  float Sreg[8];
#pragma unroll
  for (int rr = 0; rr < 8; ++rr) Sreg[rr] = S[nb + tr * 8 + rr];
  float4 pf[4];
#pragma unroll
  for (int q = 0; q < 4; ++q) {
    int cid = q * 256 + t;
    pf[q] = *(const float4*)(emb + (size_t)(cid >> 2) * DIM + (cid & 3) * 4);
  }
  for (int jt = 0; jt < KEMB / JT; ++jt) {
    float acc[8][8];
#pragma unroll
    for (int rr = 0; rr < 8; ++rr)
#pragma unroll
      for (int c = 0; c < 8; ++c) acc[rr][c] = 0.0f;
    for (int kc = 0; kc < DIM / KC; ++kc) {
      __syncthreads();
#pragma unroll
      for (int q = 0; q < 4; ++q) {
        int cid = q * 256 + t;
        int j = cid >> 2, k4 = cid & 3;
        et[(k4 * 4 + 0) * JT + j] = pf[q].x;
        et[(k4 * 4 + 1) * JT + j] = pf[q].y;
        et[(k4 * 4 + 2) * JT + j] = pf[q].z;
        et[(k4 * 4 + 3) * JT + j] = pf[q].w;
      }
      int s = jt * (DIM / KC) + kc + 1;
      if (s < (KEMB / JT) * (DIM / KC)) {
        int njt = s >> 4, nkc = s & 15;
        const float* base = emb + (size_t)njt * JT * DIM + nkc * KC;
#pragma unroll
        for (int q = 0; q < 4; ++q) {
          int cid = q * 256 + t;
          pf[q] = *(const float4*)(base + (size_t)(cid >> 2) * DIM + (cid & 3) * 4);
        }
      }
      __syncthreads();
      const float* ztk = zt + (kc * KC) * RT;
#pragma unroll
      for (int kk = 0; kk < KC; ++kk) {
        float4 z0 = *(const float4*)(ztk + kk * RT + tr * 8);
        float4 z1 = *(const float4*)(ztk + kk * RT + tr * 8 + 4);
        float2 e0 = *(const float2*)(et + kk * JT + g * 2);
        float2 e1 = *(const float2*)(et + kk * JT + 64 + g * 2);
        float2 e2 = *(const float2*)(et + kk * JT + 128 + g * 2);
        float2 e3 = *(const float2*)(et + kk * JT + 192 + g * 2);
        float zr[8] = {z0.x, z0.y, z0.z, z0.w, z1.x, z1.y, z1.z, z1.w};
        float ev[8] = {e0.x, e0.y, e1.x, e1.y, e2.x, e2.y, e3.x, e3.y};
#pragma unroll
        for (int rr = 0; rr < 8; ++rr)
#pragma unroll
          for (int c = 0; c < 8; ++c)
            acc[rr][c] = fmaf(zr[rr], ev[c], acc[rr][c]);
      }
    }
    int jb = jt * JT;
    float Ereg[8];
#pragma unroll
    for (int c = 0; c < 8; ++c)
      Ereg[c] = E[jb + (c >> 1) * 64 + g * 2 + (c & 1)];
#pragma unroll
    for (int rr = 0; rr < 8; ++rr)
#pragma unroll
      for (int c = 0; c < 8; ++c) {
        float A = Sreg[rr] + Ereg[c];
        float d = fmaf(-2.0f, acc[rr][c], A);
        int j = jb + (c >> 1) * 64 + g * 2 + (c & 1);
        if (d < bestd[rr] || (d == bestd[rr] && j < bestj[rr])) {
          bestd[rr] = d; bestj[rr] = j;
        }
      }
  }
  __syncthreads();
  float* rd = et;
  int*   rj = (int*)(et + 2048);
#pragma unroll
  for (int rr = 0; rr < 8; ++rr) {
    rd[(tr * 8 + rr) * 32 + g] = bestd[rr];
    rj[(tr * 8 + rr) * 32 + g] = bestj[rr];
  }
  __syncthreads();
  if (t < RT) {
    float bd = rd[t * 32];
    int   bj = rj[t * 32];
    for (int c = 1; c < 32; ++c) {
      float d2 = rd[t * 32 + c];
      int   j2 = rj[t * 32 + c];
      if (d2 < bd || (d2 == bd && j2 < bj)) { bd = d2; bj = j2; }
    }
    idx_out[nb + t]  = bj;
    idxf_out[nb + t] = (float)bj;
  }
}

// ---------- epilogue v2: LDS-staged gather + STE + loss ----------
// 512 blocks x 256 thr. Block = 64 rows (one b, hw chunk of 64). Stage the
// 64 gathered emb rows into LDS with coalesced 1 KB row copies (kills the
// 33M-scalar-gather pattern: 2.1 GB L2 line traffic -> 32 MB). Read phase:
// wave w handles d = dc*4 + w, lane = row; z/out coalesced 256 B; LDS read
// at row-stride 257 -> bank (lane+d)%32, 2-way = free.
#define EPAD 257
__global__ __launch_bounds__(256) void epilogue_kernel(
    const float* __restrict__ z, const float* __restrict__ emb,
    const int* __restrict__ idx, float* __restrict__ out0,
    double* __restrict__ loss_sum, int* __restrict__ done,
    float* __restrict__ out_loss) {
#pragma clang fp contract(off)
  __shared__ float eq[64 * EPAD];
  __shared__ int   iv_l[64];
  __shared__ double wsum[4];
  const int t = threadIdx.x, w = t >> 6, lane = t & 63;
  const int nb = blockIdx.x * 64;
  const int b = nb >> 10, hwb = nb & 1023;

  if (t < 64) iv_l[t] = idx[nb + t];
  __syncthreads();
  // stage: wave w copies rows w*16..+15, one coalesced 1 KB row per iter
  const float4* emb4 = (const float4*)emb;
#pragma unroll
  for (int i = 0; i < 16; ++i) {
    int r = w * 16 + i;
    float4 v = emb4[(size_t)iv_l[r] * 64 + lane];
    *(float4*)(eq + r * EPAD + lane * 4) = v;
  }
  __syncthreads();

  double acc = 0.0;
  const float* zb = z + (size_t)b * (DIM * HW_) + hwb;
  float* ob = out0 + (size_t)b * (DIM * HW_) + hwb;
  for (int dc = 0; dc < 64; ++dc) {
    int d = dc * 4 + w;
    float zp = zb[(size_t)d * HW_ + lane];
    float zq = eq[lane * EPAD + d];
    float td = zq - zp;                   // fl(z_q - zp)
    ob[(size_t)d * HW_ + lane] = zp + td; // fl(zp + fl(z_q - zp))
    acc += (double)(td * td);
  }
#pragma unroll
  for (int off = 32; off > 0; off >>= 1) acc += __shfl_down(acc, off, 64);
  if (lane == 0) wsum[w] = acc;
  __syncthreads();
  if (t == 0) {
    double bsum = (wsum[0] + wsum[1]) + (wsum[2] + wsum[3]);
    atomicAdd(loss_sum, bsum);
    __threadfence();
    int prev = atomicAdd(done, 1);
    if (prev == 511) {
      double m = loss_sum[0] / 8388608.0;
      float mf = (float)m;
      float bb = 10.0f * mf;
      out_loss[0] = mf + bb;
    }
  }
}

extern "C" void kernel_launch(void* const* d_in, const int* in_sizes, int n_in,
                              void* d_out, int out_size, void* d_ws, size_t ws_size,
                              hipStream_t stream) {
  const float* z   = (const float*)d_in[0];
  const float* emb = (const float*)d_in[1];
  float* out = (float*)d_out;
  char* ws = (char*)d_ws;
  int*      idx  = (int*)ws;
  float*    S    = (float*)(ws + WS_S_OFF);
  float*    E    = (float*)(ws + WS_E_OFF);
  double*   ls   = (double*)(ws + WS_LOSS_OFF);
  int*      done = (int*)(ws + WS_DONE_OFF);
  int*      cnt  = (int*)(ws + WS_CNT_OFF);
  int*      cand = (int*)(ws + WS_CAND_OFF);
  short*    ebuf = (short*)(ws + WS_EBUF_OFF);

  const int do_filter = (ws_size >= (size_t)WS_NEEDED) ? 1 : 0;

  prep_kernel<<<656, 256, 0, stream>>>(z, emb, S, E, ebuf, ls, done, do_filter);

  if (do_filter) {
    filter_kernel<<<512, 256, 0, stream>>>(z, ebuf, E, cnt, cand);
    exact_cand_kernel<<<128, 256, 0, stream>>>(z, emb, S, E, cnt, cand, idx,
                                               out + 8388609);
  } else {
    dist_argmin_kernel<<<NROWS / RT, 256, 0, stream>>>(z, emb, S, E, idx,
                                                       out + 8388609);
  }

  epilogue_kernel<<<512, 256, 0, stream>>>(z, emb, idx, out, ls, done,
                                           out + 8388608);
}

// Round 10
// 305.885 us; speedup vs baseline: 1.7127x; 1.3686x over previous
//
#include <hip/hip_runtime.h>

#define DIM   256
#define HW_   1024
#define NROWS 32768
#define KEMB  4096

// ---------------- ws layout ----------------
// [0,       131072)  int    idx[32768]
// [131072,  262144)  float  S[32768]
// [262144,  278528)  float  E[4096]
// [278528,  278536)  double loss_sum
// [278536,  278540)  int    done
// [278592,  409664)  int    cnt[32768]
// [540736,  1589312) int    cand[32768][8]
// [1589312, 3686464) short  ebuf[1048576]  (bf16, 16x16-frag-major, 2 MB)
#define WS_S_OFF    131072
#define WS_E_OFF    262144
#define WS_LOSS_OFF 278528
#define WS_DONE_OFF 278536
#define WS_CNT_OFF  278592
#define WS_CAND_OFF 540736
#define WS_EBUF_OFF 1589312
#define WS_NEEDED   3686464
#define RESCUE_W    1.5e-4f

typedef __attribute__((ext_vector_type(8))) short bf16x8;
typedef __attribute__((ext_vector_type(4))) float f32x4;

__device__ __forceinline__ unsigned short f2bf(float v) {
  unsigned u = __float_as_uint(v);
  return (unsigned short)((u + 0x7FFFu + ((u >> 16) & 1u)) >> 16);
}

// ---------- numpy-pairwise row sums of squares ----------
__device__ __forceinline__ float np_sumsq_128(const float* q, int stride) {
#pragma clang fp contract(off)
  float r[8];
#pragma unroll
  for (int i = 0; i < 8; ++i) { float v = q[i * stride]; r[i] = v * v; }
  for (int blk = 8; blk < 128; blk += 8) {
#pragma unroll
    for (int i = 0; i < 8; ++i) {
      float v = q[(blk + i) * stride];
      float sq = v * v;
      r[i] = r[i] + sq;
    }
  }
  return ((r[0] + r[1]) + (r[2] + r[3])) + ((r[4] + r[5]) + (r[6] + r[7]));
}

// ---------- prep: norms+init [0,144) + 16x16-frag pack [144,656) ----------
// pack (R5-proven): tile (g16, ks): lane l holds e[j = g16*16 + (l&15)]
// [k = ks*32 + (l>>4)*8 + i]; flat short offset = u*8, u = (g16*8+ks)*64+l.
__global__ __launch_bounds__(256) void prep_kernel(
    const float* __restrict__ z, const float* __restrict__ emb,
    float* __restrict__ S, float* __restrict__ E, short* __restrict__ ebuf,
    double* __restrict__ loss_sum, int* __restrict__ done, int do_filter) {
#pragma clang fp contract(off)
  if (blockIdx.x < 144) {
    int t = blockIdx.x * 256 + threadIdx.x;
    if (t == 0) { loss_sum[0] = 0.0; done[0] = 0; }
    if (t < NROWS) {
      int b = t >> 10, hw = t & 1023;
      const float* p = z + (size_t)b * (DIM * HW_) + hw;
      float s0 = np_sumsq_128(p, HW_);
      float s1 = np_sumsq_128(p + 128 * HW_, HW_);
      S[t] = s0 + s1;
    } else if (t < NROWS + KEMB) {
      int j = t - NROWS;
      const float* p = emb + (size_t)j * DIM;
      float s0 = np_sumsq_128(p, 1);
      float s1 = np_sumsq_128(p + 128, 1);
      E[j] = s0 + s1;
    }
  } else {
    if (!do_filter) return;
    int u = (blockIdx.x - 144) * 256 + threadIdx.x;   // 0..131071
    int lane = u & 63;
    int ks = (u >> 6) & 7;
    int g16 = u >> 9;
    int j = g16 * 16 + (lane & 15);
    int kb = ks * 32 + (lane >> 4) * 8;
    const float* p = emb + (size_t)j * DIM + kb;
    short out[8];
#pragma unroll
    for (int i = 0; i < 8; ++i) out[i] = (short)f2bf(p[i]);
    *(bf16x8*)(ebuf + (size_t)u * 8) = *(bf16x8*)out;
  }
}

// ---------- fused filter (R5-proven, 159 us): two-sweep 16x16x32 MFMA ----------
// 512 blocks x 4 waves; block = 64 rows. Wave w = j-quarter [w*1024,+1024).
// mt=4: A (64 rows x 256 k bf16) resident in 128 VGPRs per wave; acc[2][4]
// f32x4 = 32 regs -> fits 256/wave at 8 waves/CU. 8 independent MFMA chains
// of 8 per group. Sweep 0: exact fp32 row minima of g = E_j - 2*M_bf16.
// Sweep 1: identical MFMA recompute; emit j where g <= rowmin + W.
// A/B lane=[m: lane&15][k:(lane>>4)*8+i]; C/D col=lane&15, row=quad*4+rg
// [R3-R5 HW-verified, absmax 0].
__global__ __launch_bounds__(256, 2) void filter2_kernel(
    const float* __restrict__ z, const short* __restrict__ ebuf,
    const float* __restrict__ E, int* __restrict__ cnt_g,
    int* __restrict__ cand_g) {
  __shared__ float rowmin_l[64][4];
  __shared__ float thr_l[64];
  __shared__ int   cnt_l[64];
  __shared__ int   cand_l[64][8];

  const int t = threadIdx.x;
  const int w = t >> 6, lane = t & 63;
  const int quad = lane >> 4, l16 = lane & 15;
  const int nb = blockIdx.x * 64;
  const int b = nb >> 10, hwb = nb & 1023;   // 64 | 1024: no b straddle

  // ---- one-time A load + bf16 convert (64 rows, mt=4) ----
  bf16x8 a[4][8];
  const float* zb = z + (size_t)b * (DIM * HW_) + hwb + l16;
#pragma unroll
  for (int mt = 0; mt < 4; ++mt) {
    const float* zp = zb + mt * 16;
#pragma unroll
    for (int ks = 0; ks < 8; ++ks) {
      short tmp[8];
#pragma unroll
      for (int i = 0; i < 8; ++i)
        tmp[i] = (short)f2bf(zp[(size_t)(ks * 32 + quad * 8 + i) * HW_]);
      a[mt][ks] = *(bf16x8*)tmp;
    }
  }

  const f32x4 zero = {0.0f, 0.0f, 0.0f, 0.0f};

  // ================= sweep 0: row minima =================
  float runmin[4][4];
#pragma unroll
  for (int mt = 0; mt < 4; ++mt)
#pragma unroll
    for (int rg = 0; rg < 4; ++rg) runmin[mt][rg] = 3.0e38f;

  for (int grp = 0; grp < 32; ++grp) {
    const int jb = w * 1024 + grp * 32;
    const int g16b = jb >> 4;
    f32x4 acc[2][4];
#pragma unroll
    for (int jt = 0; jt < 2; ++jt)
#pragma unroll
      for (int mt = 0; mt < 4; ++mt) acc[jt][mt] = zero;
#pragma unroll
    for (int ks = 0; ks < 8; ++ks) {
      bf16x8 bfr[2];
#pragma unroll
      for (int jt = 0; jt < 2; ++jt)
        bfr[jt] = *(const bf16x8*)(ebuf +
            ((size_t)(g16b + jt) * 8 + ks) * 512 + lane * 8);
#pragma unroll
      for (int jt = 0; jt < 2; ++jt)
#pragma unroll
        for (int mt = 0; mt < 4; ++mt)
          acc[jt][mt] = __builtin_amdgcn_mfma_f32_16x16x32_bf16(
              a[mt][ks], bfr[jt], acc[jt][mt], 0, 0, 0);
    }
#pragma unroll
    for (int jt = 0; jt < 2; ++jt) {
      float Ej = E[jb + jt * 16 + l16];
#pragma unroll
      for (int mt = 0; mt < 4; ++mt)
#pragma unroll
        for (int rg = 0; rg < 4; ++rg) {
          float g = fmaf(-2.0f, acc[jt][mt][rg], Ej);
          runmin[mt][rg] = fminf(runmin[mt][rg], g);
        }
    }
  }
  // reduce over the 16 j-columns
#pragma unroll
  for (int mt = 0; mt < 4; ++mt)
#pragma unroll
    for (int rg = 0; rg < 4; ++rg) {
      float m = runmin[mt][rg];
#pragma unroll
      for (int mask = 1; mask <= 8; mask <<= 1)
        m = fminf(m, __shfl_xor(m, mask, 64));
      runmin[mt][rg] = m;
    }
  if (l16 == 0) {
#pragma unroll
    for (int mt = 0; mt < 4; ++mt)
#pragma unroll
      for (int rg = 0; rg < 4; ++rg)
        rowmin_l[mt * 16 + quad * 4 + rg][w] = runmin[mt][rg];
  }
  __syncthreads();
  if (t < 64) {
    float m = fminf(fminf(rowmin_l[t][0], rowmin_l[t][1]),
                    fminf(rowmin_l[t][2], rowmin_l[t][3]));
    thr_l[t] = m + RESCUE_W;
    cnt_l[t] = 0;
  }
  __syncthreads();
  float thrv[4][4];
#pragma unroll
  for (int mt = 0; mt < 4; ++mt)
#pragma unroll
    for (int rg = 0; rg < 4; ++rg)
      thrv[mt][rg] = thr_l[mt * 16 + quad * 4 + rg];

  // ================= sweep 1: emission =================
  for (int grp = 0; grp < 32; ++grp) {
    const int jb = w * 1024 + grp * 32;
    const int g16b = jb >> 4;
    f32x4 acc[2][4];
#pragma unroll
    for (int jt = 0; jt < 2; ++jt)
#pragma unroll
      for (int mt = 0; mt < 4; ++mt) acc[jt][mt] = zero;
#pragma unroll
    for (int ks = 0; ks < 8; ++ks) {
      bf16x8 bfr[2];
#pragma unroll
      for (int jt = 0; jt < 2; ++jt)
        bfr[jt] = *(const bf16x8*)(ebuf +
            ((size_t)(g16b + jt) * 8 + ks) * 512 + lane * 8);
#pragma unroll
      for (int jt = 0; jt < 2; ++jt)
#pragma unroll
        for (int mt = 0; mt < 4; ++mt)
          acc[jt][mt] = __builtin_amdgcn_mfma_f32_16x16x32_bf16(
              a[mt][ks], bfr[jt], acc[jt][mt], 0, 0, 0);
    }
#pragma unroll
    for (int jt = 0; jt < 2; ++jt) {
      int jcol = jb + jt * 16 + l16;
      float Ej = E[jcol];
#pragma unroll
      for (int mt = 0; mt < 4; ++mt)
#pragma unroll
        for (int rg = 0; rg < 4; ++rg) {
          float g = fmaf(-2.0f, acc[jt][mt][rg], Ej);
          if (g <= thrv[mt][rg]) {
            int rl = mt * 16 + quad * 4 + rg;
            int slot = atomicAdd(&cnt_l[rl], 1);
            if (slot < 8) cand_l[rl][slot] = jcol;
          }
        }
    }
  }
  __syncthreads();
  if (t < 64) {
    int c = cnt_l[t];
    cnt_g[nb + t] = c;
    int cc = c > 8 ? 8 : c;
    for (int p = 0; p < cc; ++p) cand_g[(size_t)(nb + t) * 8 + p] = cand_l[t][p];
  }
}

// ---------- rescue: exact np-order chains over per-row candidates ----------
__global__ __launch_bounds__(256) void exact_cand_kernel(
    const float* __restrict__ z, const float* __restrict__ emb,
    const float* __restrict__ S, const float* __restrict__ E,
    const int* __restrict__ cnt_g, const int* __restrict__ cand_g,
    int* __restrict__ idx_out, float* __restrict__ idxf_out) {
  int row = blockIdx.x * 256 + threadIdx.x;
  int b = row >> 10, hw = row & 1023;
  const float* zr = z + (size_t)b * (DIM * HW_) + hw;   // z[k] at zr[k*1024]
  const float s = S[row];
  int c = cnt_g[row];
  float bd = 3.0e38f; int bj = 0x7fffffff;
  if (c <= 8) {
    for (int p = 0; p < c; ++p) {
      int j = cand_g[(size_t)row * 8 + p];
      const float* e = emb + (size_t)j * DIM;
      float acc = 0.0f;
#pragma unroll 8
      for (int k4 = 0; k4 < 64; ++k4) {          // sequential k ascending
        float4 ev = *(const float4*)(e + k4 * 4);
        acc = fmaf(zr[(size_t)(k4 * 4 + 0) * HW_], ev.x, acc);
        acc = fmaf(zr[(size_t)(k4 * 4 + 1) * HW_], ev.y, acc);
        acc = fmaf(zr[(size_t)(k4 * 4 + 2) * HW_], ev.z, acc);
        acc = fmaf(zr[(size_t)(k4 * 4 + 3) * HW_], ev.w, acc);
      }
      float d = fmaf(-2.0f, acc, s + E[j]);
      if (d < bd || (d == bd && j < bj)) { bd = d; bj = j; }
    }
  } else {
    for (int j = 0; j < KEMB; ++j) {             // overflow fallback (P~0)
      const float* e = emb + (size_t)j * DIM;
      float acc = 0.0f;
      for (int k4 = 0; k4 < 64; ++k4) {
        float4 ev = *(const float4*)(e + k4 * 4);
        acc = fmaf(zr[(size_t)(k4 * 4 + 0) * HW_], ev.x, acc);
        acc = fmaf(zr[(size_t)(k4 * 4 + 1) * HW_], ev.y, acc);
        acc = fmaf(zr[(size_t)(k4 * 4 + 2) * HW_], ev.z, acc);
        acc = fmaf(zr[(size_t)(k4 * 4 + 3) * HW_], ev.w, acc);
      }
      float d = fmaf(-2.0f, acc, s + E[j]);
      if (d < bd || (d == bd && j < bj)) { bd = d; bj = j; }
    }
  }
  idx_out[row] = bj;
  idxf_out[row] = (float)bj;
}

// ---------- fallback fp32 kernel (R2 version, known-passing) ----------
#define RT 64
#define JT 256
#define KC 16
__global__ __launch_bounds__(256, 2) void dist_argmin_kernel(
    const float* __restrict__ z, const float* __restrict__ emb,
    const float* __restrict__ S, const float* __restrict__ E,
    int* __restrict__ idx_out, float* __restrict__ idxf_out) {
  __shared__ float zt[DIM * RT];
  __shared__ float et[KC * JT];
  const int t  = threadIdx.x;
  const int g  = t & 31;
  const int tr = t >> 5;
  const int nb = blockIdx.x * RT;
  const int b  = nb >> 10;
  const int hwb = nb & 1023;
  const float* zb = z + (size_t)b * (DIM * HW_) + hwb;
#pragma unroll
  for (int i = 0; i < 16; ++i) {
    int flat = t + i * 256;
    int k  = flat >> 4;
    int r4 = flat & 15;
    float4 v = *(const float4*)(zb + (size_t)k * HW_ + r4 * 4);
    *(float4*)(zt + flat * 4) = v;
  }
  float bestd[8];
  int   bestj[8];
#pragma unroll
  for (int i = 0; i < 8; ++i) { bestd[i] = 3.0e38f; bestj[i] = 0; }
  float Sreg[8];
#pragma unroll
  for (int rr = 0; rr < 8; ++rr) Sreg[rr] = S[nb + tr * 8 + rr];
  float4 pf[4];
#pragma unroll
  for (int q = 0; q < 4; ++q) {
    int cid = q * 256 + t;
    pf[q] = *(const float4*)(emb + (size_t)(cid >> 2) * DIM + (cid & 3) * 4);
  }
  for (int jt = 0; jt < KEMB / JT; ++jt) {
    float acc[8][8];
#pragma unroll
    for (int rr = 0; rr < 8; ++rr)
#pragma unroll
      for (int c = 0; c < 8; ++c) acc[rr][c] = 0.0f;
    for (int kc = 0; kc < DIM / KC; ++kc) {
      __syncthreads();
#pragma unroll
      for (int q = 0; q < 4; ++q) {
        int cid = q * 256 + t;
        int j = cid >> 2, k4 = cid & 3;
        et[(k4 * 4 + 0) * JT + j] = pf[q].x;
        et[(k4 * 4 + 1) * JT + j] = pf[q].y;
        et[(k4 * 4 + 2) * JT + j] = pf[q].z;
        et[(k4 * 4 + 3) * JT + j] = pf[q].w;
      }
      int s = jt * (DIM / KC) + kc + 1;
      if (s < (KEMB / JT) * (DIM / KC)) {
        int njt = s >> 4, nkc = s & 15;
        const float* base = emb + (size_t)njt * JT * DIM + nkc * KC;
#pragma unroll
        for (int q = 0; q < 4; ++q) {
          int cid = q * 256 + t;
          pf[q] = *(const float4*)(base + (size_t)(cid >> 2) * DIM + (cid & 3) * 4);
        }
      }
      __syncthreads();
      const float* ztk = zt + (kc * KC) * RT;
#pragma unroll
      for (int kk = 0; kk < KC; ++kk) {
        float4 z0 = *(const float4*)(ztk + kk * RT + tr * 8);
        float4 z1 = *(const float4*)(ztk + kk * RT + tr * 8 + 4);
        float2 e0 = *(const float2*)(et + kk * JT + g * 2);
        float2 e1 = *(const float2*)(et + kk * JT + 64 + g * 2);
        float2 e2 = *(const float2*)(et + kk * JT + 128 + g * 2);
        float2 e3 = *(const float2*)(et + kk * JT + 192 + g * 2);
        float zr[8] = {z0.x, z0.y, z0.z, z0.w, z1.x, z1.y, z1.z, z1.w};
        float ev[8] = {e0.x, e0.y, e1.x, e1.y, e2.x, e2.y, e3.x, e3.y};
#pragma unroll
        for (int rr = 0; rr < 8; ++rr)
#pragma unroll
          for (int c = 0; c < 8; ++c)
            acc[rr][c] = fmaf(zr[rr], ev[c], acc[rr][c]);
      }
    }
    int jb = jt * JT;
    float Ereg[8];
#pragma unroll
    for (int c = 0; c < 8; ++c)
      Ereg[c] = E[jb + (c >> 1) * 64 + g * 2 + (c & 1)];
#pragma unroll
    for (int rr = 0; rr < 8; ++rr)
#pragma unroll
      for (int c = 0; c < 8; ++c) {
        float A = Sreg[rr] + Ereg[c];
        float d = fmaf(-2.0f, acc[rr][c], A);
        int j = jb + (c >> 1) * 64 + g * 2 + (c & 1);
        if (d < bestd[rr] || (d == bestd[rr] && j < bestj[rr])) {
          bestd[rr] = d; bestj[rr] = j;
        }
      }
  }
  __syncthreads();
  float* rd = et;
  int*   rj = (int*)(et + 2048);
#pragma unroll
  for (int rr = 0; rr < 8; ++rr) {
    rd[(tr * 8 + rr) * 32 + g] = bestd[rr];
    rj[(tr * 8 + rr) * 32 + g] = bestj[rr];
  }
  __syncthreads();
  if (t < RT) {
    float bd = rd[t * 32];
    int   bj = rj[t * 32];
    for (int c = 1; c < 32; ++c) {
      float d2 = rd[t * 32 + c];
      int   j2 = rj[t * 32 + c];
      if (d2 < bd || (d2 == bd && j2 < bj)) { bd = d2; bj = j2; }
    }
    idx_out[nb + t]  = bj;
    idxf_out[nb + t] = (float)bj;
  }
}

// ---------- epilogue v2 (R9-proven): LDS-staged gather + STE + loss ----------
#define EPAD 257
__global__ __launch_bounds__(256) void epilogue_kernel(
    const float* __restrict__ z, const float* __restrict__ emb,
    const int* __restrict__ idx, float* __restrict__ out0,
    double* __restrict__ loss_sum, int* __restrict__ done,
    float* __restrict__ out_loss) {
#pragma clang fp contract(off)
  __shared__ float eq[64 * EPAD];
  __shared__ int   iv_l[64];
  __shared__ double wsum[4];
  const int t = threadIdx.x, w = t >> 6, lane = t & 63;
  const int nb = blockIdx.x * 64;
  const int b = nb >> 10, hwb = nb & 1023;

  if (t < 64) iv_l[t] = idx[nb + t];
  __syncthreads();
  const float4* emb4 = (const float4*)emb;
#pragma unroll
  for (int i = 0; i < 16; ++i) {
    int r = w * 16 + i;
    float4 v = emb4[(size_t)iv_l[r] * 64 + lane];
    *(float4*)(eq + r * EPAD + lane * 4) = v;
  }
  __syncthreads();

  double acc = 0.0;
  const float* zb = z + (size_t)b * (DIM * HW_) + hwb;
  float* ob = out0 + (size_t)b * (DIM * HW_) + hwb;
  for (int dc = 0; dc < 64; ++dc) {
    int d = dc * 4 + w;
    float zp = zb[(size_t)d * HW_ + lane];
    float zq = eq[lane * EPAD + d];
    float td = zq - zp;                   // fl(z_q - zp)
    ob[(size_t)d * HW_ + lane] = zp + td; // fl(zp + fl(z_q - zp))
    acc += (double)(td * td);
  }
#pragma unroll
  for (int off = 32; off > 0; off >>= 1) acc += __shfl_down(acc, off, 64);
  if (lane == 0) wsum[w] = acc;
  __syncthreads();
  if (t == 0) {
    double bsum = (wsum[0] + wsum[1]) + (wsum[2] + wsum[3]);
    atomicAdd(loss_sum, bsum);
    __threadfence();
    int prev = atomicAdd(done, 1);
    if (prev == 511) {
      double m = loss_sum[0] / 8388608.0;
      float mf = (float)m;
      float bb = 10.0f * mf;
      out_loss[0] = mf + bb;
    }
  }
}

extern "C" void kernel_launch(void* const* d_in, const int* in_sizes, int n_in,
                              void* d_out, int out_size, void* d_ws, size_t ws_size,
                              hipStream_t stream) {
  const float* z   = (const float*)d_in[0];
  const float* emb = (const float*)d_in[1];
  float* out = (float*)d_out;
  char* ws = (char*)d_ws;
  int*      idx  = (int*)ws;
  float*    S    = (float*)(ws + WS_S_OFF);
  float*    E    = (float*)(ws + WS_E_OFF);
  double*   ls   = (double*)(ws + WS_LOSS_OFF);
  int*      done = (int*)(ws + WS_DONE_OFF);
  int*      cnt  = (int*)(ws + WS_CNT_OFF);
  int*      cand = (int*)(ws + WS_CAND_OFF);
  short*    ebuf = (short*)(ws + WS_EBUF_OFF);

  const int do_filter = (ws_size >= (size_t)WS_NEEDED) ? 1 : 0;

  prep_kernel<<<656, 256, 0, stream>>>(z, emb, S, E, ebuf, ls, done, do_filter);

  if (do_filter) {
    filter2_kernel<<<512, 256, 0, stream>>>(z, ebuf, E, cnt, cand);
    exact_cand_kernel<<<128, 256, 0, stream>>>(z, emb, S, E, cnt, cand, idx,
                                               out + 8388609);
  } else {
    dist_argmin_kernel<<<NROWS / RT, 256, 0, stream>>>(z, emb, S, E, idx,
                                                       out + 8388609);
  }

  epilogue_kernel<<<512, 256, 0, stream>>>(z, emb, idx, out, ls, done,
                                           out + 8388608);
}